// Round 1
// baseline (919.861 us; speedup 1.0000x reference)
//
#include <hip/hip_runtime.h>

#define NNODE 50000
#define NEDGE 800000
#define NH 4
#define DH 64
#define HD 256  // NH*DH

typedef __attribute__((ext_vector_type(8))) short short8v;
typedef __attribute__((ext_vector_type(4))) float float4v;

static __device__ __forceinline__ float b2f(unsigned short u) {
  union { float f; unsigned v; } x; x.v = ((unsigned)u) << 16; return x.f;
}
static __device__ __forceinline__ unsigned short f2b(float f) {
  unsigned u = __builtin_bit_cast(unsigned, f);
  u += 0x7fff + ((u >> 16) & 1);  // RNE
  return (unsigned short)(u >> 16);
}

// ---------------- CSR build ----------------
__global__ void k_hist(const int* __restrict__ dst, int* __restrict__ deg) {
  int e = blockIdx.x * blockDim.x + threadIdx.x;
  if (e < NEDGE) atomicAdd(&deg[dst[e]], 1);
}

__global__ __launch_bounds__(1024) void k_scan(const int* __restrict__ deg,
                                               int* __restrict__ rowptr, int n) {
  __shared__ int sdata[1024];
  int carry = 0;
  if (threadIdx.x == 0) rowptr[0] = 0;
  for (int base = 0; base < n; base += 1024) {
    int i = base + threadIdx.x;
    int v = (i < n) ? deg[i] : 0;
    sdata[threadIdx.x] = v;
    __syncthreads();
    for (int off = 1; off < 1024; off <<= 1) {
      int t = (threadIdx.x >= off) ? sdata[threadIdx.x - off] : 0;
      __syncthreads();
      sdata[threadIdx.x] += t;
      __syncthreads();
    }
    if (i < n) rowptr[i + 1] = carry + sdata[threadIdx.x];
    carry += sdata[1023];
    __syncthreads();
  }
}

__global__ void k_scatter(const int* __restrict__ src, const int* __restrict__ dst,
                          const int* __restrict__ rowptr, int* __restrict__ fill,
                          int* __restrict__ csr_src) {
  int e = blockIdx.x * blockDim.x + threadIdx.x;
  if (e < NEDGE) {
    int d = dst[e];
    int pos = rowptr[d] + atomicAdd(&fill[d], 1);
    csr_src[pos] = src[e];
  }
}

// ---------------- GEMM: feat = A @ W, bf16 MFMA, fp32 accum ----------------
// Block: 256 threads = 4 waves; block computes 64 rows x 256 cols.
// Wave w handles head w (cols w*64 .. w*64+63): acc[4][4] of 16x16 frags.
__global__ __launch_bounds__(256) void k_gemm(const float* __restrict__ A,
                                              const float* __restrict__ W,
                                              unsigned short* __restrict__ featb) {
  __shared__ unsigned short As[64][32];   // [m][k] bf16
  __shared__ unsigned short Bs[256][32];  // [n][k] bf16 (transposed)
  int row0 = blockIdx.x * 64;
  int tid = threadIdx.x;
  int lane = tid & 63;
  int head = tid >> 6;

  float4v acc[4][4] = {};

  for (int k0 = 0; k0 < 256; k0 += 32) {
    // stage A: 64x32 fp32 -> bf16, 8 elems/thread
    {
      int r = tid >> 2;
      int c = (tid & 3) * 8;
      bool valid = (row0 + r) < NNODE;
      const float* ap = A + (size_t)(row0 + r) * HD + k0 + c;
#pragma unroll
      for (int j = 0; j < 8; ++j)
        As[r][c + j] = f2b(valid ? ap[j] : 0.f);
    }
    // stage B transposed: W[k0+kk][c0..c0+31] -> Bs[col][kk]
    {
      int kk = tid >> 3;
      int c0 = (tid & 7) * 32;
      const float* wp = W + (size_t)(k0 + kk) * HD + c0;
#pragma unroll
      for (int j = 0; j < 32; ++j)
        Bs[c0 + j][kk] = f2b(wp[j]);
    }
    __syncthreads();

    int lr = lane & 15;
    int kf = (lane >> 4) * 8;
    short8v af[4], bfr[4];
#pragma unroll
    for (int mi = 0; mi < 4; ++mi)
      af[mi] = *(const short8v*)&As[mi * 16 + lr][kf];
#pragma unroll
    for (int ni = 0; ni < 4; ++ni)
      bfr[ni] = *(const short8v*)&Bs[head * 64 + ni * 16 + lr][kf];
#pragma unroll
    for (int mi = 0; mi < 4; ++mi)
#pragma unroll
      for (int ni = 0; ni < 4; ++ni)
        acc[mi][ni] = __builtin_amdgcn_mfma_f32_16x16x32_bf16(af[mi], bfr[ni], acc[mi][ni], 0, 0, 0);
    __syncthreads();
  }

  // epilogue: D row=(lane>>4)*4+reg + mi*16, col = head*64 + ni*16 + (lane&15)
  int lr = lane & 15;
  int rg = (lane >> 4) * 4;
#pragma unroll
  for (int mi = 0; mi < 4; ++mi) {
#pragma unroll
    for (int reg = 0; reg < 4; ++reg) {
      int grow = row0 + mi * 16 + rg + reg;
      if (grow < NNODE) {
#pragma unroll
        for (int ni = 0; ni < 4; ++ni)
          featb[(size_t)grow * HD + head * 64 + ni * 16 + lr] = f2b(acc[mi][ni][reg]);
      }
    }
  }
}

// ---------------- el/er: [N,H] dots of feat rows with al/ar ----------------
__global__ __launch_bounds__(256) void k_eler(const unsigned short* __restrict__ featb,
                                              const float* __restrict__ al,
                                              const float* __restrict__ ar,
                                              float* __restrict__ el,
                                              float* __restrict__ er) {
  int tid = threadIdx.x;
  int lane = tid & 63;
  int w = tid >> 6;
  int n = blockIdx.x * 4 + w;
  if (n >= NNODE) return;
  int head = lane >> 4;
  int cc = (lane & 15) * 4;  // col within head
  const unsigned short* fp = featb + (size_t)n * HD + head * 64 + cc;
  float e1 = 0.f, e2 = 0.f;
#pragma unroll
  for (int j = 0; j < 4; ++j) {
    float v = b2f(fp[j]);
    e1 += v * al[head * 64 + cc + j];
    e2 += v * ar[head * 64 + cc + j];
  }
#pragma unroll
  for (int off = 1; off < 16; off <<= 1) {
    e1 += __shfl_xor(e1, off, 64);
    e2 += __shfl_xor(e2, off, 64);
  }
  if ((lane & 15) == 0) {
    el[n * NH + head] = e1;
    er[n * NH + head] = e2;
  }
}

// ---------------- fused softmax + aggregate + residual (+relu/mean) -------
// Block = node, wave = head, lane = feature d. Online softmax over CSR list.
template <int LAYER>
__global__ __launch_bounds__(256) void k_agg(const int* __restrict__ rowptr,
                                             const int* __restrict__ csr_src,
                                             const float* __restrict__ el,
                                             const float* __restrict__ er,
                                             const unsigned short* __restrict__ featb,
                                             const float* __restrict__ hin,
                                             const float* __restrict__ bias,
                                             float* __restrict__ out) {
  int n = blockIdx.x;
  int tid = threadIdx.x;
  int h = tid >> 6;
  int d = tid & 63;
  int rs = rowptr[n], re_ = rowptr[n + 1];
  float ernh = er[n * NH + h];
  float m = -INFINITY, den = 0.f, acc = 0.f;
  for (int i = rs; i < re_; ++i) {
    int s = csr_src[i];
    float e = el[s * NH + h] + ernh;
    e = e > 0.f ? e : 0.2f * e;  // leaky_relu 0.2
    float mn = fmaxf(m, e);
    float sc = __expf(m - mn);  // exp(-inf)=0 on first iter
    float p = __expf(e - mn);
    den = den * sc + p;
    float fv = b2f(featb[(size_t)s * HD + h * 64 + d]);
    acc = acc * sc + p * fv;
    m = mn;
  }
  float v = (den > 0.f) ? acc / den : 0.f;
  v += hin[(size_t)n * HD + h * 64 + d] + bias[h * 64 + d];
  if (LAYER == 2) {
    __shared__ float red[NH][DH];
    v = fmaxf(v, 0.f);
    red[h][d] = v;
    __syncthreads();
    if (tid < 64)
      out[(size_t)n * DH + tid] =
          0.25f * (red[0][tid] + red[1][tid] + red[2][tid] + red[3][tid]);
  } else {
    out[(size_t)n * HD + h * 64 + d] = v;
  }
}

extern "C" void kernel_launch(void* const* d_in, const int* in_sizes, int n_in,
                              void* d_out, int out_size, void* d_ws, size_t ws_size,
                              hipStream_t stream) {
  const float* features = (const float*)d_in[0];
  const int* src = (const int*)d_in[1];
  const int* dst = (const int*)d_in[2];
  const float* W0 = (const float*)d_in[3];
  const float* al0 = (const float*)d_in[4];
  const float* ar0 = (const float*)d_in[5];
  const float* b0 = (const float*)d_in[6];
  const float* W1 = (const float*)d_in[7];
  const float* al1 = (const float*)d_in[8];
  const float* ar1 = (const float*)d_in[9];
  const float* b1 = (const float*)d_in[10];
  const float* W2 = (const float*)d_in[11];
  const float* al2 = (const float*)d_in[12];
  const float* ar2 = (const float*)d_in[13];
  const float* b2 = (const float*)d_in[14];
  float* out = (float*)d_out;

  char* p = (char*)d_ws;
  float* h1 = (float*)p;                 p += (size_t)NNODE * HD * 4;
  float* h2 = (float*)p;                 p += (size_t)NNODE * HD * 4;
  unsigned short* featb = (unsigned short*)p; p += (size_t)NNODE * HD * 2;
  float* el = (float*)p;                 p += (size_t)NNODE * NH * 4;
  float* er = (float*)p;                 p += (size_t)NNODE * NH * 4;
  int* deg = (int*)p;                    p += (size_t)NNODE * 4;
  int* fill = (int*)p;                   p += (size_t)NNODE * 4;
  int* rowptr = (int*)p;                 p += (size_t)(NNODE + 1) * 4;
  int* csr = (int*)p;                    p += (size_t)NEDGE * 4;

  // zero deg + fill (adjacent)
  hipMemsetAsync(deg, 0, (size_t)NNODE * 4 * 2, stream);

  int eblocks = (NEDGE + 255) / 256;
  k_hist<<<eblocks, 256, 0, stream>>>(dst, deg);
  k_scan<<<1, 1024, 0, stream>>>(deg, rowptr, NNODE);
  k_scatter<<<eblocks, 256, 0, stream>>>(src, dst, rowptr, fill, csr);

  dim3 gg((NNODE + 63) / 64);

  // layer 0
  k_gemm<<<gg, 256, 0, stream>>>(features, W0, featb);
  k_eler<<<NNODE / 4, 256, 0, stream>>>(featb, al0, ar0, el, er);
  k_agg<0><<<NNODE, 256, 0, stream>>>(rowptr, csr, el, er, featb, features, b0, h1);
  // layer 1
  k_gemm<<<gg, 256, 0, stream>>>(h1, W1, featb);
  k_eler<<<NNODE / 4, 256, 0, stream>>>(featb, al1, ar1, el, er);
  k_agg<1><<<NNODE, 256, 0, stream>>>(rowptr, csr, el, er, featb, h1, b1, h2);
  // layer 2
  k_gemm<<<gg, 256, 0, stream>>>(h2, W2, featb);
  k_eler<<<NNODE / 4, 256, 0, stream>>>(featb, al2, ar2, el, er);
  k_agg<2><<<NNODE, 256, 0, stream>>>(rowptr, csr, el, er, featb, h2, b2, out);
}

// Round 2
// 593.314 us; speedup vs baseline: 1.5504x; 1.5504x over previous
//
#include <hip/hip_runtime.h>

#define NNODE 50000
#define NEDGE 800000
#define NH 4
#define DH 64
#define HD 256      // NH*DH
#define PADN 50048  // 782 * 64

typedef __attribute__((ext_vector_type(8))) short short8v;
typedef __attribute__((ext_vector_type(4))) float float4v;
typedef __attribute__((ext_vector_type(4))) unsigned short ushort4v;

static __device__ __forceinline__ float b2f(unsigned short u) {
  union { float f; unsigned v; } x; x.v = ((unsigned)u) << 16; return x.f;
}
static __device__ __forceinline__ unsigned short f2b(float f) {
  unsigned u = __builtin_bit_cast(unsigned, f);
  u += 0x7fff + ((u >> 16) & 1);  // RNE
  return (unsigned short)(u >> 16);
}

// ---------------- fp32 -> bf16 convert (features) ----------------
__global__ __launch_bounds__(256) void k_cvt(const float* __restrict__ in,
                                             unsigned short* __restrict__ outb) {
  int i = (blockIdx.x * 256 + threadIdx.x) * 4;  // grid covers exactly N*HD
  float4v v = *(const float4v*)(in + i);
  ushort4v o;
  o.x = f2b(v.x); o.y = f2b(v.y); o.z = f2b(v.z); o.w = f2b(v.w);
  *(ushort4v*)(outb + i) = o;
}

// ---------------- W [k][n] fp32 -> Wt [n][k] bf16, 3 layers ----------------
__global__ __launch_bounds__(256) void k_cvtw(const float* __restrict__ W0,
                                              const float* __restrict__ W1,
                                              const float* __restrict__ W2,
                                              unsigned short* __restrict__ T0,
                                              unsigned short* __restrict__ T1,
                                              unsigned short* __restrict__ T2) {
  const float* W = blockIdx.y == 0 ? W0 : (blockIdx.y == 1 ? W1 : W2);
  unsigned short* T = blockIdx.y == 0 ? T0 : (blockIdx.y == 1 ? T1 : T2);
  int k = blockIdx.x;      // coalesced read of W row k
  int nn = threadIdx.x;
  T[nn * HD + k] = f2b(W[k * HD + nn]);
}

// ---------------- CSR build ----------------
__global__ void k_hist(const int* __restrict__ dst, int* __restrict__ deg) {
  int e = blockIdx.x * blockDim.x + threadIdx.x;
  if (e < NEDGE) atomicAdd(&deg[dst[e]], 1);
}

__global__ __launch_bounds__(1024) void k_scan(const int* __restrict__ deg,
                                               int* __restrict__ rowptr) {
  const int C = (NNODE + 1023) / 1024;  // 49
  int t = threadIdx.x;
  int lo = t * C;
  int hi = min(lo + C, NNODE);
  int sum = 0;
  for (int i = lo; i < hi; ++i) sum += deg[i];
  int lane = t & 63, w = t >> 6;
  int pre = sum;
#pragma unroll
  for (int off = 1; off < 64; off <<= 1) {
    int v = __shfl_up(pre, off, 64);
    if (lane >= off) pre += v;
  }
  __shared__ int wsum[16];
  __shared__ int woff[17];
  if (lane == 63) wsum[w] = pre;
  __syncthreads();
  if (t == 0) {
    int a = 0;
    for (int i = 0; i < 16; ++i) { woff[i] = a; a += wsum[i]; }
    woff[16] = a;
  }
  __syncthreads();
  int run = woff[w] + (pre - sum);  // exclusive prefix for this thread's chunk
  for (int i = lo; i < hi; ++i) { rowptr[i] = run; run += deg[i]; }
  if (t == 0) rowptr[NNODE] = woff[16];
}

__global__ void k_scatter(const int* __restrict__ src, const int* __restrict__ dst,
                          const int* __restrict__ rowptr, int* __restrict__ fill,
                          int* __restrict__ csr_src) {
  int e = blockIdx.x * blockDim.x + threadIdx.x;
  if (e < NEDGE) {
    int d = dst[e];
    int pos = rowptr[d] + atomicAdd(&fill[d], 1);
    csr_src[pos] = src[e];
  }
}

// ---------------- GEMM: featb = Ab @ Wt^T (bf16 MFMA), fused el/er ----------
// Block 256 = 4 waves; 64 rows x 256 cols; wave = head (64 cols).
// A staged via global_load_lds (double-buffered); B frags straight from L2-hot Wt.
__global__ __launch_bounds__(256) void k_gemm(const unsigned short* __restrict__ Ab,
                                              const unsigned short* __restrict__ Wt,
                                              const float* __restrict__ al,
                                              const float* __restrict__ ar,
                                              unsigned short* __restrict__ featb,
                                              float* __restrict__ el,
                                              float* __restrict__ er) {
  __shared__ unsigned short As[2][64][32];
  const int row0 = blockIdx.x * 64;
  const int tid = threadIdx.x;
  const int lane = tid & 63;
  const int head = tid >> 6;
  const int lr = lane & 15;
  const int kf = (lane >> 4) * 8;

  const unsigned short* gsrc = Ab + (size_t)(row0 + (tid >> 2)) * HD + (tid & 3) * 8;
  unsigned short* ld0 = &As[0][tid >> 2][(tid & 3) * 8];
  unsigned short* ld1 = &As[1][tid >> 2][(tid & 3) * 8];

#define STAGE(dstp, t)                                                              \
  __builtin_amdgcn_global_load_lds(                                                 \
      (const __attribute__((address_space(1))) unsigned int*)(gsrc + (t) * 32),     \
      (__attribute__((address_space(3))) unsigned int*)(dstp), 16, 0, 0)

  float4v acc[4][4] = {};

  STAGE(ld0, 0);
#pragma unroll
  for (int t = 0; t < 8; ++t) {
    __syncthreads();  // stage t complete (vmcnt drain), all waves synced
    if (t < 7) STAGE((t & 1) ? ld0 : ld1, t + 1);
    const int buf = t & 1;
    short8v af[4], bfr[4];
#pragma unroll
    for (int ni = 0; ni < 4; ++ni)
      bfr[ni] = *(const short8v*)(Wt + (size_t)(head * 64 + ni * 16 + lr) * HD + t * 32 + kf);
#pragma unroll
    for (int mi = 0; mi < 4; ++mi)
      af[mi] = *(const short8v*)&As[buf][mi * 16 + lr][kf];
#pragma unroll
    for (int mi = 0; mi < 4; ++mi)
#pragma unroll
      for (int ni = 0; ni < 4; ++ni)
        acc[mi][ni] = __builtin_amdgcn_mfma_f32_16x16x32_bf16(af[mi], bfr[ni], acc[mi][ni], 0, 0, 0);
  }
#undef STAGE

  // epilogue: C row = mi*16 + (lane>>4)*4 + reg, col = head*64 + ni*16 + lr
  float alv[4], arv[4];
#pragma unroll
  for (int ni = 0; ni < 4; ++ni) {
    alv[ni] = al[head * 64 + ni * 16 + lr];
    arv[ni] = ar[head * 64 + ni * 16 + lr];
  }
  const int rg = (lane >> 4) * 4;
#pragma unroll
  for (int mi = 0; mi < 4; ++mi) {
#pragma unroll
    for (int reg = 0; reg < 4; ++reg) {
      int grow = row0 + mi * 16 + rg + reg;
      bool valid = grow < NNODE;
      float e1 = 0.f, e2 = 0.f;
#pragma unroll
      for (int ni = 0; ni < 4; ++ni) {
        float v = acc[mi][ni][reg];
        e1 = fmaf(v, alv[ni], e1);
        e2 = fmaf(v, arv[ni], e2);
        if (valid) featb[(size_t)grow * HD + head * 64 + ni * 16 + lr] = f2b(v);
      }
#pragma unroll
      for (int off = 1; off < 16; off <<= 1) {
        e1 += __shfl_xor(e1, off, 64);
        e2 += __shfl_xor(e2, off, 64);
      }
      if (lr == 0 && valid) {
        el[grow * NH + head] = e1;
        er[grow * NH + head] = e2;
      }
    }
  }
}

// ---------------- fused softmax + aggregate + residual (+relu/mean) -------
// Block = node, wave = head, lane = edge (softmax phase) then feature (agg phase).
template <int LAYER>
__global__ __launch_bounds__(256) void k_agg(const int* __restrict__ rowptr,
                                             const int* __restrict__ csr_src,
                                             const float* __restrict__ el,
                                             const float* __restrict__ er,
                                             const unsigned short* __restrict__ featb,
                                             const unsigned short* __restrict__ hinb,
                                             const float* __restrict__ bias,
                                             void* __restrict__ outv) {
  const int n = blockIdx.x;
  const int tid = threadIdx.x;
  const int h = tid >> 6;
  const int lane = tid & 63;
  const int rs = rowptr[n], re_ = rowptr[n + 1];
  const float ernh = er[n * NH + h];

  __shared__ float alpha_s[NH][64];
  __shared__ int src_s[NH][64];

  float den = 0.f, acc = 0.f;
  const int deg = re_ - rs;

  if (deg > 0 && deg <= 64) {
    // fast path: whole softmax in one chunk, lane = edge
    int s = 0; float e = -1e30f;
    if (lane < deg) {
      s = csr_src[rs + lane];
      float x = el[s * NH + h] + ernh;
      e = x > 0.f ? x : 0.2f * x;
    }
    float m = e;
#pragma unroll
    for (int off = 32; off; off >>= 1) m = fmaxf(m, __shfl_xor(m, off, 64));
    float p = (lane < deg) ? __expf(e - m) : 0.f;
    alpha_s[h][lane] = p;
    src_s[h][lane] = s;
    float ps = p;
#pragma unroll
    for (int off = 32; off; off >>= 1) ps += __shfl_xor(ps, off, 64);
    den = ps;
    // aggregation: lane = feature d; 4 accumulators for ILP
    int j = 0;
    float a0 = 0.f, a1 = 0.f, a2 = 0.f, a3 = 0.f;
    for (; j + 4 <= deg; j += 4) {
      int s0 = src_s[h][j], s1 = src_s[h][j + 1], s2 = src_s[h][j + 2], s3 = src_s[h][j + 3];
      float f0 = b2f(featb[(s0 << 8) + (h << 6) + lane]);
      float f1 = b2f(featb[(s1 << 8) + (h << 6) + lane]);
      float f2 = b2f(featb[(s2 << 8) + (h << 6) + lane]);
      float f3 = b2f(featb[(s3 << 8) + (h << 6) + lane]);
      a0 = fmaf(alpha_s[h][j], f0, a0);
      a1 = fmaf(alpha_s[h][j + 1], f1, a1);
      a2 = fmaf(alpha_s[h][j + 2], f2, a2);
      a3 = fmaf(alpha_s[h][j + 3], f3, a3);
    }
    for (; j < deg; ++j)
      a0 = fmaf(alpha_s[h][j], b2f(featb[(src_s[h][j] << 8) + (h << 6) + lane]), a0);
    acc = (a0 + a1) + (a2 + a3);
  } else if (deg > 64) {
    // general path: two passes, chunked
    float m = -1e30f;
    for (int base = rs; base < re_; base += 64) {
      int i = base + lane;
      float e = -1e30f;
      if (i < re_) {
        float x = el[csr_src[i] * NH + h] + ernh;
        e = x > 0.f ? x : 0.2f * x;
      }
#pragma unroll
      for (int off = 32; off; off >>= 1) e = fmaxf(e, __shfl_xor(e, off, 64));
      m = fmaxf(m, e);
    }
    for (int base = rs; base < re_; base += 64) {
      int i = base + lane;
      int cn = min(64, re_ - base);
      float p = 0.f; int s = 0;
      if (i < re_) {
        s = csr_src[i];
        float x = el[s * NH + h] + ernh;
        x = x > 0.f ? x : 0.2f * x;
        p = __expf(x - m);
      }
      alpha_s[h][lane] = p;
      src_s[h][lane] = s;
      float ps = p;
#pragma unroll
      for (int off = 32; off; off >>= 1) ps += __shfl_xor(ps, off, 64);
      den += ps;
      for (int j = 0; j < cn; ++j)
        acc = fmaf(alpha_s[h][j], b2f(featb[(src_s[h][j] << 8) + (h << 6) + lane]), acc);
    }
  }

  float v = (den > 0.f) ? acc / den : 0.f;
  v += b2f(hinb[(n << 8) + (h << 6) + lane]) + bias[(h << 6) + lane];

  if (LAYER == 2) {
    __shared__ float red[NH][DH];
    red[h][lane] = fmaxf(v, 0.f);
    __syncthreads();
    float* out = (float*)outv;
    if (tid < 64)
      out[(size_t)n * DH + tid] =
          0.25f * (red[0][tid] + red[1][tid] + red[2][tid] + red[3][tid]);
  } else {
    unsigned short* outb = (unsigned short*)outv;
    outb[(n << 8) + (h << 6) + lane] = f2b(v);
  }
}

extern "C" void kernel_launch(void* const* d_in, const int* in_sizes, int n_in,
                              void* d_out, int out_size, void* d_ws, size_t ws_size,
                              hipStream_t stream) {
  const float* features = (const float*)d_in[0];
  const int* src = (const int*)d_in[1];
  const int* dst = (const int*)d_in[2];
  const float* W0 = (const float*)d_in[3];
  const float* al0 = (const float*)d_in[4];
  const float* ar0 = (const float*)d_in[5];
  const float* b0 = (const float*)d_in[6];
  const float* W1 = (const float*)d_in[7];
  const float* al1 = (const float*)d_in[8];
  const float* ar1 = (const float*)d_in[9];
  const float* b1 = (const float*)d_in[10];
  const float* W2 = (const float*)d_in[11];
  const float* al2 = (const float*)d_in[12];
  const float* ar2 = (const float*)d_in[13];
  const float* b2 = (const float*)d_in[14];
  float* out = (float*)d_out;

  char* p = (char*)d_ws;
  auto carve = [&](size_t bytes) {
    char* q = p;
    p += (bytes + 255) & ~(size_t)255;
    return q;
  };
  unsigned short* h0b = (unsigned short*)carve((size_t)PADN * HD * 2);
  unsigned short* h1b = (unsigned short*)carve((size_t)PADN * HD * 2);
  unsigned short* h2b = (unsigned short*)carve((size_t)PADN * HD * 2);
  unsigned short* featb = (unsigned short*)carve((size_t)PADN * HD * 2);
  unsigned short* wt0 = (unsigned short*)carve((size_t)HD * HD * 2);
  unsigned short* wt1 = (unsigned short*)carve((size_t)HD * HD * 2);
  unsigned short* wt2 = (unsigned short*)carve((size_t)HD * HD * 2);
  float* el = (float*)carve((size_t)NNODE * NH * 4);
  float* er = (float*)carve((size_t)NNODE * NH * 4);
  int* deg = (int*)carve((size_t)NNODE * 4 * 2);  // deg + fill contiguous
  int* fill = deg + NNODE;
  int* rowptr = (int*)carve((size_t)(NNODE + 1) * 4);
  int* csr = (int*)carve((size_t)NEDGE * 4);

  hipMemsetAsync(deg, 0, (size_t)NNODE * 4 * 2, stream);

  k_cvt<<<NNODE * HD / (256 * 4), 256, 0, stream>>>(features, h0b);
  k_cvtw<<<dim3(HD, 3), 256, 0, stream>>>(W0, W1, W2, wt0, wt1, wt2);

  int eblocks = NEDGE / 256;
  k_hist<<<eblocks, 256, 0, stream>>>(dst, deg);
  k_scan<<<1, 1024, 0, stream>>>(deg, rowptr);
  k_scatter<<<eblocks, 256, 0, stream>>>(src, dst, rowptr, fill, csr);

  dim3 gg(PADN / 64);

  k_gemm<<<gg, 256, 0, stream>>>(h0b, wt0, al0, ar0, featb, el, er);
  k_agg<0><<<NNODE, 256, 0, stream>>>(rowptr, csr, el, er, featb, h0b, b0, h1b);

  k_gemm<<<gg, 256, 0, stream>>>(h1b, wt1, al1, ar1, featb, el, er);
  k_agg<1><<<NNODE, 256, 0, stream>>>(rowptr, csr, el, er, featb, h1b, b1, h2b);

  k_gemm<<<gg, 256, 0, stream>>>(h2b, wt2, al2, ar2, featb, el, er);
  k_agg<2><<<NNODE, 256, 0, stream>>>(rowptr, csr, el, er, featb, h2b, b2, (void*)out);
}